// Round 17
// baseline (202.352 us; speedup 1.0000x reference)
//
#include <hip/hip_runtime.h>
#include <hip/hip_bf16.h>
#include <math.h>

#define N_EMBD 1024
#define N_HEAD 16
#define HS 64
#define BT 4096
#define TSEQ 2048

typedef float f32x4 __attribute__((ext_vector_type(4)));
typedef short bf16x8 __attribute__((ext_vector_type(8)));
typedef unsigned short u16;

static __device__ __forceinline__ u16 f2bf(float f) {
  union { float f; unsigned int u; } c; c.f = f;
  unsigned int r = c.u + 0x7FFFu + ((c.u >> 16) & 1u);   // RNE
  return (u16)(r >> 16);
}

static __device__ __forceinline__ u16 f2bf_fast(float f) {
  union { __hip_bfloat16 h; u16 u; } cv;
  cv.h = __float2bfloat16(f);
  return cv.u;
}

// ---------------- fused prep: x->bf16 ; W_attn,W_proj -> bf16 transposed
__global__ __launch_bounds__(256) void prep_all(
    const float* __restrict__ x, const float* __restrict__ Wa,
    const float* __restrict__ Wp, u16* __restrict__ xb,
    u16* __restrict__ Wat, u16* __restrict__ Wpt) {
  const int bid = blockIdx.x;
  const int t = threadIdx.x;
  if (bid < 4096) {
    int i = bid * 256 + t;
    float4 v = ((const float4*)x)[i];
    ushort4 o;
    o.x = f2bf(v.x); o.y = f2bf(v.y); o.z = f2bf(v.z); o.w = f2bf(v.w);
    ((ushort4*)xb)[i] = o;
    return;
  }
  __shared__ u16 Ls[32][36];
  const float* W; u16* Wt; int K, N, n0, k0;
  if (bid < 7168) {
    int g = bid - 4096;                       // 96 x 32
    W = Wa; Wt = Wat; K = N_EMBD; N = 3 * N_EMBD;
    n0 = (g % 96) * 32; k0 = (g / 96) * 32;
  } else {
    int g = bid - 7168;                       // 32 x 32
    W = Wp; Wt = Wpt; K = N_EMBD; N = N_EMBD;
    n0 = (g % 32) * 32; k0 = (g / 32) * 32;
  }
  {
    int kk = t >> 3, nn4 = (t & 7) * 4;
    float4 v = *(const float4*)(W + (size_t)(k0 + kk) * N + n0 + nn4);
    Ls[kk][nn4 + 0] = f2bf(v.x); Ls[kk][nn4 + 1] = f2bf(v.y);
    Ls[kk][nn4 + 2] = f2bf(v.z); Ls[kk][nn4 + 3] = f2bf(v.w);
  }
  __syncthreads();
  {
    int nn = t >> 3, kk4 = (t & 7) * 4;
    ushort4 o;
    o.x = Ls[kk4 + 0][nn]; o.y = Ls[kk4 + 1][nn];
    o.z = Ls[kk4 + 2][nn]; o.w = Ls[kk4 + 3][nn];
    *(ushort4*)(Wt + (size_t)(n0 + nn) * K + k0 + kk4) = o;
  }
}

// ---------------- bf16 MFMA GEMM core (m97 structure + T1 XCD swizzle)
#define BKS 32

__device__ __forceinline__ int swz(int row, int c) {
  return row * 4 + (c ^ ((row >> 1) & 3));
}

__device__ __forceinline__ void stage128x32(const u16* __restrict__ G, int ldk,
                                            u16* lds, int w, int lane) {
#pragma unroll
  for (int i = 0; i < 2; ++i) {
    int s = i * 256 + w * 64 + lane;
    int row = s >> 2, c = s & 3;
    int csrc = c ^ ((row >> 1) & 3);
    const u16* src = G + (size_t)row * ldk + csrc * 8;
    u16* dst = lds + (size_t)(i * 256 + w * 64) * 8;
    __builtin_amdgcn_global_load_lds(
        (const __attribute__((address_space(1))) void*)src,
        (__attribute__((address_space(3))) void*)dst, 16, 0, 0);
  }
}

#define GEMM_MAIN_LOOP(Aptr, Bptr, Kdim)                                        \
  __shared__ u16 sm[2][2][128 * BKS];                                           \
  const int tid = threadIdx.x, lane = tid & 63, w = tid >> 6;                   \
  const int wr = w >> 1, wc = w & 1, lrow = lane & 15, lhi = lane >> 4;         \
  const int _lin = blockIdx.y * gridDim.x + blockIdx.x;                         \
  const int _cpx = (gridDim.x * gridDim.y) >> 3;                                \
  const int _swz = (_lin & 7) * _cpx + (_lin >> 3);                             \
  const int bm = (_swz / gridDim.x) * 128, bn = (_swz % gridDim.x) * 128;       \
  f32x4 acc[4][4];                                                              \
  _Pragma("unroll") for (int i = 0; i < 4; ++i)                                 \
      _Pragma("unroll") for (int j = 0; j < 4; ++j)                             \
          acc[i][j] = (f32x4){0.f, 0.f, 0.f, 0.f};                              \
  stage128x32(Aptr + (size_t)bm * Kdim, Kdim, sm[0][0], w, lane);               \
  stage128x32(Bptr + (size_t)bn * Kdim, Kdim, sm[0][1], w, lane);               \
  __syncthreads();                                                              \
  const int NT = Kdim / BKS;                                                    \
  for (int t = 0; t < NT; ++t) {                                                \
    int cur = t & 1, nxt = cur ^ 1;                                             \
    if (t + 1 < NT) {                                                           \
      stage128x32(Aptr + (size_t)bm * Kdim + (t + 1) * BKS, Kdim, sm[nxt][0],   \
                  w, lane);                                                     \
      stage128x32(Bptr + (size_t)bn * Kdim + (t + 1) * BKS, Kdim, sm[nxt][1],   \
                  w, lane);                                                     \
    }                                                                           \
    const u16* As = sm[cur][0];                                                 \
    const u16* Bs = sm[cur][1];                                                 \
    bf16x8 af[4], bfr[4];                                                       \
    _Pragma("unroll") for (int mi = 0; mi < 4; ++mi) {                          \
      int row = wr * 64 + mi * 16 + lrow;                                       \
      af[mi] = *(const bf16x8*)(As + (size_t)swz(row, lhi) * 8);                \
    }                                                                           \
    _Pragma("unroll") for (int nj = 0; nj < 4; ++nj) {                          \
      int row = wc * 64 + nj * 16 + lrow;                                       \
      bfr[nj] = *(const bf16x8*)(Bs + (size_t)swz(row, lhi) * 8);               \
    }                                                                           \
    _Pragma("unroll") for (int mi = 0; mi < 4; ++mi)                            \
        _Pragma("unroll") for (int nj = 0; nj < 4; ++nj)                        \
            acc[mi][nj] = __builtin_amdgcn_mfma_f32_16x16x32_bf16(              \
                af[mi], bfr[nj], acc[mi][nj], 0, 0, 0);                         \
    __syncthreads();                                                            \
  }

// QKV GEMM epilogue -> Qb (scaled by 0.125*log2e), Kb, Vt
__global__ __launch_bounds__(256) void gemm_qkv_bf16(
    const u16* __restrict__ Ab, const u16* __restrict__ Btr,
    const float* __restrict__ bias,
    u16* __restrict__ Qb, u16* __restrict__ Kb, u16* __restrict__ Vt) {
  GEMM_MAIN_LOOP(Ab, Btr, N_EMBD)
  const int sector = bn >> 10;
  const float QSC = 0.125f * 1.44269504f;
#pragma unroll
  for (int nj = 0; nj < 4; ++nj) {
    int n = bn + wc * 64 + nj * 16 + lrow;
    int h = (n & 1023) >> 6, d = n & 63;
    float bv = bias[n];
#pragma unroll
    for (int mi = 0; mi < 4; ++mi) {
      int mbase = bm + wr * 64 + mi * 16 + lhi * 4;
      int bb_ = mbase >> 11, tt = mbase & 2047;
      if (sector == 0) {
#pragma unroll
        for (int r = 0; r < 4; ++r)
          Qb[((size_t)(bb_ * 16 + h) * TSEQ + tt + r) * HS + d] =
              f2bf((acc[mi][nj][r] + bv) * QSC);
      } else if (sector == 1) {
#pragma unroll
        for (int r = 0; r < 4; ++r)
          Kb[((size_t)(bb_ * 16 + h) * TSEQ + tt + r) * HS + d] =
              f2bf(acc[mi][nj][r] + bv);
      } else {
        ushort4 o;
        o.x = f2bf(acc[mi][nj][0] + bv); o.y = f2bf(acc[mi][nj][1] + bv);
        o.z = f2bf(acc[mi][nj][2] + bv); o.w = f2bf(acc[mi][nj][3] + bv);
        *(ushort4*)(Vt + ((size_t)(bb_ * 16 + h) * HS + d) * TSEQ + tt) = o;
      }
    }
  }
}

// Proj GEMM epilogue -> fp32 out + bias
__global__ __launch_bounds__(256) void gemm_proj_bf16(
    const u16* __restrict__ Ab, const u16* __restrict__ Btr,
    const float* __restrict__ bias, float* __restrict__ C) {
  GEMM_MAIN_LOOP(Ab, Btr, N_EMBD)
#pragma unroll
  for (int nj = 0; nj < 4; ++nj) {
    int n = bn + wc * 64 + nj * 16 + lrow;
    float bv = bias[n];
#pragma unroll
    for (int mi = 0; mi < 4; ++mi) {
      int mbase = bm + wr * 64 + mi * 16 + lhi * 4;
#pragma unroll
      for (int r = 0; r < 4; ++r)
        C[(size_t)(mbase + r) * N_EMBD + n] = acc[mi][nj][r] + bv;
    }
  }
}

// ---------------- MFMA flash attention v13: 64 q-rows per wave
// Block = 4 waves x 64 rows = 256 rows; per bh 8 q-blocks (tsteps=4j+4).
// K/V LDS reads reused across 4 subtiles -> LDS bytes per MFMA halved
// (72 MFMA per wave-step vs 36). Split plan: j<=2,1,0 direct; j3,j4 2-way;
// j5,j6 3-way; j7 4-way = 17 units/bh, 544 blocks, longest-first.
// fp32 partials (448 x 64KB); first 224 slots overlay dead xb+Wat.
__device__ __forceinline__ void stage_kv(const u16* __restrict__ Kh,
                                         const u16* __restrict__ Vh,
                                         int kb, u16* kbuf, u16* vbuf,
                                         int tid, int w) {
#pragma unroll
  for (int i = 0; i < 2; ++i) {
    int s = i * 256 + tid;
    int r = s >> 3, c = s & 7;
    int cs = c ^ (r & 7);                      // pre-swizzled global source
    const u16* ksrc = Kh + (size_t)(kb + r) * HS + cs * 8;
    u16* kdst = kbuf + (size_t)(i * 256 + (w << 6)) * 8;   // wave-uniform base
    __builtin_amdgcn_global_load_lds(
        (const __attribute__((address_space(1))) void*)ksrc,
        (__attribute__((address_space(3))) void*)kdst, 16, 0, 0);
    const u16* vsrc = Vh + (size_t)r * TSEQ + kb + cs * 8;
    u16* vdst = vbuf + (size_t)(i * 256 + (w << 6)) * 8;
    __builtin_amdgcn_global_load_lds(
        (const __attribute__((address_space(1))) void*)vsrc,
        (__attribute__((address_space(3))) void*)vdst, 16, 0, 0);
  }
}

__global__ __launch_bounds__(256, 2) void attn_part(
    const u16* __restrict__ Qb, const u16* __restrict__ Kb,
    const u16* __restrict__ Vt, u16* __restrict__ Y,
    float* PfLow, float* PfHi, float* __restrict__ Lf) {
  __shared__ u16 Ks[2][64 * HS];      // 32KB dbuf
  __shared__ u16 Vs[2][64 * HS];
  __shared__ u16 Plds[4][64][72];     // 36.9KB

  const int tid  = threadIdx.x;
  const int lane = tid & 63;
  const int w    = tid >> 6;
  const int lrow = lane & 15;
  const int lhi  = lane >> 4;

  const int wg  = blockIdx.x;                 // 0..543
  const int xcd = wg & 7;
  const int lin = wg >> 3;                    // 0..67
  const int bhl = lin / 17;                   // 0..3
  const int id  = lin % 17;
  const int bh  = (xcd << 2) | bhl;
  const int b   = bh >> 4, h = bh & 15;

  // longest-first unit decode
  int j, part, cnt, sid;
  if (id == 0)       { j = 2; part = 0;       cnt = 1; sid = -1; }      // 12
  else if (id <= 2)  { j = 4; part = id - 1;  cnt = 2; sid = id - 1; }  // 10,10
  else if (id <= 5)  { j = 6; part = id - 3;  cnt = 3; sid = id - 1; }  // 9,9,10
  else if (id <= 7)  { j = 3; part = id - 6;  cnt = 2; sid = id - 1; }  // 8,8
  else if (id <= 11) { j = 7; part = id - 8;  cnt = 4; sid = id - 1; }  // 8x4
  else if (id <= 14) { j = 5; part = id - 12; cnt = 3; sid = id - 1; }  // 8x3
  else if (id == 15) { j = 1; part = 0;       cnt = 1; sid = -1; }      // 8
  else               { j = 0; part = 0;       cnt = 1; sid = -1; }      // 4
  const int split  = (cnt > 1);
  const int tsteps = 4 * j + 4;
  const int s0 = (part * tsteps) / cnt;
  const int s1 = ((part + 1) * tsteps) / cnt;
  const int nsteps = s1 - s0;

  const u16* Qh = Qb + (size_t)bh * TSEQ * HS;
  const u16* Kh = Kb + (size_t)bh * TSEQ * HS;
  const u16* Vh = Vt + (size_t)bh * HS * TSEQ;

  const int q0 = j * 256 + w * 64;            // wave's rows q0..q0+63

  bf16x8 aq[8];
#pragma unroll
  for (int sub = 0; sub < 4; ++sub) {
    aq[2 * sub]     = *(const bf16x8*)(Qh + (size_t)(q0 + sub * 16 + lrow) * HS + lhi * 8);
    aq[2 * sub + 1] = *(const bf16x8*)(Qh + (size_t)(q0 + sub * 16 + lrow) * HS + 32 + lhi * 8);
  }

  bf16x8 ones;
#pragma unroll
  for (int i = 0; i < 8; ++i) ones[i] = (short)0x3F80;   // bf16 1.0

  f32x4 o[4][4], ol[4];
#pragma unroll
  for (int sub = 0; sub < 4; ++sub) {
    ol[sub] = (f32x4){0.f, 0.f, 0.f, 0.f};
#pragma unroll
    for (int ds = 0; ds < 4; ++ds) o[sub][ds] = (f32x4){0.f, 0.f, 0.f, 0.f};
  }

  int kb = s0 * 64;
  stage_kv(Kh, Vh, kb, Ks[0], Vs[0], tid, w);

  for (int t = 0; t < nsteps; ++t) {
    const int cur = t & 1;
    __syncthreads();
    if (t + 1 < nsteps)
      stage_kv(Kh, Vh, kb + 64, Ks[cur ^ 1], Vs[cur ^ 1], tid, w);

    const u16* Kc = Ks[cur];
    const u16* Vc = Vs[cur];

    // ---- phase A: QK^T — K frags shared across 4 subtiles
    f32x4 sacc[4][4];
#pragma unroll
    for (int s = 0; s < 4; ++s) {
      int r = s * 16 + lrow;
      bf16x8 k0 = *(const bf16x8*)(Kc + r * HS + ((lhi    ) ^ (r & 7)) * 8);
      bf16x8 k1 = *(const bf16x8*)(Kc + r * HS + ((lhi + 4) ^ (r & 7)) * 8);
#pragma unroll
      for (int sub = 0; sub < 4; ++sub) {
        f32x4 z = (f32x4){0.f, 0.f, 0.f, 0.f};
        z = __builtin_amdgcn_mfma_f32_16x16x32_bf16(aq[2 * sub], k0, z, 0, 0, 0);
        z = __builtin_amdgcn_mfma_f32_16x16x32_bf16(aq[2 * sub + 1], k1, z, 0, 0, 0);
        sacc[sub][s] = z;
      }
    }

    // ---- mask + static-max exp2 + P write
#pragma unroll
    for (int sub = 0; sub < 4; ++sub) {
      const int qbase = q0 + sub * 16;
      if (kb + 63 > qbase) {
#pragma unroll
        for (int s = 0; s < 4; ++s) {
          int kg = kb + 16 * s + lrow;
#pragma unroll
          for (int r = 0; r < 4; ++r)
            if (kg > qbase + lhi * 4 + r) sacc[sub][s][r] = -3.0e38f;
        }
      }
#pragma unroll
      for (int s = 0; s < 4; ++s)
#pragma unroll
        for (int r = 0; r < 4; ++r)
          Plds[w][sub * 16 + lhi * 4 + r][s * 16 + lrow] =
              f2bf_fast(exp2f(sacc[sub][s][r] - 16.0f));
    }

    // ---- phase B: PV + ones-column l — V frags shared across 4 subtiles
#pragma unroll
    for (int ks = 0; ks < 2; ++ks) {
      bf16x8 pa[4];
#pragma unroll
      for (int sub = 0; sub < 4; ++sub)
        pa[sub] = *(const bf16x8*)&Plds[w][sub * 16 + lrow][ks * 32 + lhi * 8];
#pragma unroll
      for (int sub = 0; sub < 4; ++sub)
        ol[sub] = __builtin_amdgcn_mfma_f32_16x16x32_bf16(pa[sub], ones, ol[sub], 0, 0, 0);
#pragma unroll
      for (int ds = 0; ds < 4; ++ds) {
        int vr = ds * 16 + lrow;
        bf16x8 vf = *(const bf16x8*)(Vc + vr * 64 + ((ks * 4 + lhi) ^ (vr & 7)) * 8);
#pragma unroll
        for (int sub = 0; sub < 4; ++sub)
          o[sub][ds] = __builtin_amdgcn_mfma_f32_16x16x32_bf16(pa[sub], vf, o[sub][ds], 0, 0, 0);
      }
    }
    kb += 64;
  }

  if (!split) {
    // ---- direct epilogue
#pragma unroll
    for (int sub = 0; sub < 4; ++sub)
#pragma unroll
      for (int r = 0; r < 4; ++r) {
        float inv = 1.0f / ol[sub][r];
        int q = q0 + sub * 16 + lhi * 4 + r;
#pragma unroll
        for (int ds = 0; ds < 4; ++ds)
          Y[((size_t)(b * TSEQ + q)) * N_EMBD + h * HS + ds * 16 + lrow] =
              f2bf(o[sub][ds][r] * inv);
      }
  } else {
    // ---- partial epilogue: fp32 o + f32 l (static-max scale: add to combine)
    const int slot = bh * 14 + sid;
    float* orow = (slot < 224)
                      ? (PfLow + (size_t)slot * 16384)
                      : (PfHi + (size_t)(slot - 224) * 16384);
#pragma unroll
    for (int sub = 0; sub < 4; ++sub)
#pragma unroll
      for (int r = 0; r < 4; ++r) {
        int row = w * 64 + sub * 16 + lhi * 4 + r;
#pragma unroll
        for (int ds = 0; ds < 4; ++ds)
          orow[row * 64 + ds * 16 + lrow] = o[sub][ds][r];
        if (lrow == 0) Lf[slot * 256 + row] = ol[sub][r];
      }
  }
}

// combine: one block per split q-block (bh, j in {3..7}); sum parts, normalize.
__global__ __launch_bounds__(256) void attn_combine(
    const float* PfLow, const float* PfHi, const float* __restrict__ Lf,
    u16* __restrict__ Y) {
  const int bi = blockIdx.x;                  // 0..159
  const int bh = bi / 5, u = bi % 5;
  const int b  = bh >> 4, h = bh & 15;
  int j, base, cnt;
  if (u == 0)      { j = 3; base = 5;  cnt = 2; }
  else if (u == 1) { j = 4; base = 0;  cnt = 2; }
  else if (u == 2) { j = 5; base = 11; cnt = 3; }
  else if (u == 3) { j = 6; base = 2;  cnt = 3; }
  else             { j = 7; base = 7;  cnt = 4; }
  const int slot0 = bh * 14 + base;

  const int tid = threadIdx.x;
  const int d   = tid & 63;
  const int rg  = tid >> 6;                   // 0..3

  for (int rr = 0; rr < 64; ++rr) {
    int row = rg * 64 + rr;
    float l = 0.f, o = 0.f;
    for (int k = 0; k < cnt; ++k) {
      int slot = slot0 + k;
      const float* orow = (slot < 224)
                              ? (PfLow + (size_t)slot * 16384)
                              : (PfHi + (size_t)(slot - 224) * 16384);
      l += Lf[slot * 256 + row];
      o += orow[row * 64 + d];
    }
    int q = j * 256 + row;
    Y[((size_t)(b * TSEQ + q)) * N_EMBD + h * HS + d] = f2bf(o / l);
  }
}

extern "C" void kernel_launch(void* const* d_in, const int* in_sizes, int n_in,
                              void* d_out, int out_size, void* d_ws, size_t ws_size,
                              hipStream_t stream) {
  const float* x      = (const float*)d_in[0];
  const float* W_attn = (const float*)d_in[1];
  const float* b_attn = (const float*)d_in[2];
  const float* W_proj = (const float*)d_in[3];
  const float* b_proj = (const float*)d_in[4];
  float* out = (float*)d_out;

  u16* xb  = (u16*)d_ws;                              // dead after QKV GEMM
  u16* Wat = xb  + (size_t)BT * N_EMBD;               // dead after QKV GEMM
  u16* Wpt = Wat + (size_t)3 * N_EMBD * N_EMBD;       // kept (proj)
  u16* Qb  = Wpt + (size_t)N_EMBD * N_EMBD;
  u16* Kb  = Qb  + (size_t)BT * N_EMBD;
  u16* Vt  = Kb  + (size_t)BT * N_EMBD;
  u16* yb  = Vt  + (size_t)BT * N_EMBD;
  float* PfLow = (float*)d_ws;                        // 224 slots overlay xb+Wat (exact)
  float* PfHi  = (float*)(yb + (size_t)BT * N_EMBD);  // 224 slots * 64KB = 14.68MB
  float* Lf    = PfHi + (size_t)224 * 16384;          // 448*256 f32 = 0.46MB

  prep_all<<<8192, 256, 0, stream>>>(x, W_attn, W_proj, xb, Wat, Wpt);
  {
    dim3 grid(3 * N_EMBD / 128, BT / 128);
    gemm_qkv_bf16<<<grid, 256, 0, stream>>>(xb, Wat, b_attn, Qb, Kb, Vt);
  }
  {
    attn_part<<<544, 256, 0, stream>>>(Qb, Kb, Vt, yb, PfLow, PfHi, Lf);
    attn_combine<<<160, 256, 0, stream>>>(PfLow, PfHi, Lf, yb);
  }
  {
    dim3 grid(N_EMBD / 128, BT / 128);
    gemm_proj_bf16<<<grid, 256, 0, stream>>>(yb, Wpt, b_proj, out);
  }
}

// Round 18
// 137.328 us; speedup vs baseline: 1.4735x; 1.4735x over previous
//
#include <hip/hip_runtime.h>
#include <hip/hip_bf16.h>
#include <math.h>

#define N_EMBD 1024
#define N_HEAD 16
#define HS 64
#define BT 4096
#define TSEQ 2048

typedef float f32x4 __attribute__((ext_vector_type(4)));
typedef short bf16x8 __attribute__((ext_vector_type(8)));
typedef unsigned short u16;

static __device__ __forceinline__ u16 f2bf(float f) {
  union { float f; unsigned int u; } c; c.f = f;
  unsigned int r = c.u + 0x7FFFu + ((c.u >> 16) & 1u);   // RNE
  return (u16)(r >> 16);
}

static __device__ __forceinline__ u16 f2bf_fast(float f) {
  union { __hip_bfloat16 h; u16 u; } cv;
  cv.h = __float2bfloat16(f);
  return cv.u;
}

// ---------------- fused prep: x->bf16 ; W_attn,W_proj -> bf16 transposed
__global__ __launch_bounds__(256) void prep_all(
    const float* __restrict__ x, const float* __restrict__ Wa,
    const float* __restrict__ Wp, u16* __restrict__ xb,
    u16* __restrict__ Wat, u16* __restrict__ Wpt) {
  const int bid = blockIdx.x;
  const int t = threadIdx.x;
  if (bid < 4096) {
    int i = bid * 256 + t;
    float4 v = ((const float4*)x)[i];
    ushort4 o;
    o.x = f2bf(v.x); o.y = f2bf(v.y); o.z = f2bf(v.z); o.w = f2bf(v.w);
    ((ushort4*)xb)[i] = o;
    return;
  }
  __shared__ u16 Ls[32][36];
  const float* W; u16* Wt; int K, N, n0, k0;
  if (bid < 7168) {
    int g = bid - 4096;                       // 96 x 32
    W = Wa; Wt = Wat; K = N_EMBD; N = 3 * N_EMBD;
    n0 = (g % 96) * 32; k0 = (g / 96) * 32;
  } else {
    int g = bid - 7168;                       // 32 x 32
    W = Wp; Wt = Wpt; K = N_EMBD; N = N_EMBD;
    n0 = (g % 32) * 32; k0 = (g / 32) * 32;
  }
  {
    int kk = t >> 3, nn4 = (t & 7) * 4;
    float4 v = *(const float4*)(W + (size_t)(k0 + kk) * N + n0 + nn4);
    Ls[kk][nn4 + 0] = f2bf(v.x); Ls[kk][nn4 + 1] = f2bf(v.y);
    Ls[kk][nn4 + 2] = f2bf(v.z); Ls[kk][nn4 + 3] = f2bf(v.w);
  }
  __syncthreads();
  {
    int nn = t >> 3, kk4 = (t & 7) * 4;
    ushort4 o;
    o.x = Ls[kk4 + 0][nn]; o.y = Ls[kk4 + 1][nn];
    o.z = Ls[kk4 + 2][nn]; o.w = Ls[kk4 + 3][nn];
    *(ushort4*)(Wt + (size_t)(n0 + nn) * K + k0 + kk4) = o;
  }
}

// ---------------- bf16 MFMA GEMM core (m97 structure + T1 XCD swizzle)
#define BKS 32

__device__ __forceinline__ int swz(int row, int c) {
  return row * 4 + (c ^ ((row >> 1) & 3));
}

__device__ __forceinline__ void stage128x32(const u16* __restrict__ G, int ldk,
                                            u16* lds, int w, int lane) {
#pragma unroll
  for (int i = 0; i < 2; ++i) {
    int s = i * 256 + w * 64 + lane;
    int row = s >> 2, c = s & 3;
    int csrc = c ^ ((row >> 1) & 3);
    const u16* src = G + (size_t)row * ldk + csrc * 8;
    u16* dst = lds + (size_t)(i * 256 + w * 64) * 8;
    __builtin_amdgcn_global_load_lds(
        (const __attribute__((address_space(1))) void*)src,
        (__attribute__((address_space(3))) void*)dst, 16, 0, 0);
  }
}

#define GEMM_MAIN_LOOP(Aptr, Bptr, Kdim)                                        \
  __shared__ u16 sm[2][2][128 * BKS];                                           \
  const int tid = threadIdx.x, lane = tid & 63, w = tid >> 6;                   \
  const int wr = w >> 1, wc = w & 1, lrow = lane & 15, lhi = lane >> 4;         \
  const int _lin = blockIdx.y * gridDim.x + blockIdx.x;                         \
  const int _cpx = (gridDim.x * gridDim.y) >> 3;                                \
  const int _swz = (_lin & 7) * _cpx + (_lin >> 3);                             \
  const int bm = (_swz / gridDim.x) * 128, bn = (_swz % gridDim.x) * 128;       \
  f32x4 acc[4][4];                                                              \
  _Pragma("unroll") for (int i = 0; i < 4; ++i)                                 \
      _Pragma("unroll") for (int j = 0; j < 4; ++j)                             \
          acc[i][j] = (f32x4){0.f, 0.f, 0.f, 0.f};                              \
  stage128x32(Aptr + (size_t)bm * Kdim, Kdim, sm[0][0], w, lane);               \
  stage128x32(Bptr + (size_t)bn * Kdim, Kdim, sm[0][1], w, lane);               \
  __syncthreads();                                                              \
  const int NT = Kdim / BKS;                                                    \
  for (int t = 0; t < NT; ++t) {                                                \
    int cur = t & 1, nxt = cur ^ 1;                                             \
    if (t + 1 < NT) {                                                           \
      stage128x32(Aptr + (size_t)bm * Kdim + (t + 1) * BKS, Kdim, sm[nxt][0],   \
                  w, lane);                                                     \
      stage128x32(Bptr + (size_t)bn * Kdim + (t + 1) * BKS, Kdim, sm[nxt][1],   \
                  w, lane);                                                     \
    }                                                                           \
    const u16* As = sm[cur][0];                                                 \
    const u16* Bs = sm[cur][1];                                                 \
    bf16x8 af[4], bfr[4];                                                       \
    _Pragma("unroll") for (int mi = 0; mi < 4; ++mi) {                          \
      int row = wr * 64 + mi * 16 + lrow;                                       \
      af[mi] = *(const bf16x8*)(As + (size_t)swz(row, lhi) * 8);                \
    }                                                                           \
    _Pragma("unroll") for (int nj = 0; nj < 4; ++nj) {                          \
      int row = wc * 64 + nj * 16 + lrow;                                       \
      bfr[nj] = *(const bf16x8*)(Bs + (size_t)swz(row, lhi) * 8);               \
    }                                                                           \
    _Pragma("unroll") for (int mi = 0; mi < 4; ++mi)                            \
        _Pragma("unroll") for (int nj = 0; nj < 4; ++nj)                        \
            acc[mi][nj] = __builtin_amdgcn_mfma_f32_16x16x32_bf16(              \
                af[mi], bfr[nj], acc[mi][nj], 0, 0, 0);                         \
    __syncthreads();                                                            \
  }

// QKV GEMM epilogue -> Qb (scaled by 0.125*log2e), Kb, Vt
__global__ __launch_bounds__(256) void gemm_qkv_bf16(
    const u16* __restrict__ Ab, const u16* __restrict__ Btr,
    const float* __restrict__ bias,
    u16* __restrict__ Qb, u16* __restrict__ Kb, u16* __restrict__ Vt) {
  GEMM_MAIN_LOOP(Ab, Btr, N_EMBD)
  const int sector = bn >> 10;
  const float QSC = 0.125f * 1.44269504f;
#pragma unroll
  for (int nj = 0; nj < 4; ++nj) {
    int n = bn + wc * 64 + nj * 16 + lrow;
    int h = (n & 1023) >> 6, d = n & 63;
    float bv = bias[n];
#pragma unroll
    for (int mi = 0; mi < 4; ++mi) {
      int mbase = bm + wr * 64 + mi * 16 + lhi * 4;
      int bb_ = mbase >> 11, tt = mbase & 2047;
      if (sector == 0) {
#pragma unroll
        for (int r = 0; r < 4; ++r)
          Qb[((size_t)(bb_ * 16 + h) * TSEQ + tt + r) * HS + d] =
              f2bf((acc[mi][nj][r] + bv) * QSC);
      } else if (sector == 1) {
#pragma unroll
        for (int r = 0; r < 4; ++r)
          Kb[((size_t)(bb_ * 16 + h) * TSEQ + tt + r) * HS + d] =
              f2bf(acc[mi][nj][r] + bv);
      } else {
        ushort4 o;
        o.x = f2bf(acc[mi][nj][0] + bv); o.y = f2bf(acc[mi][nj][1] + bv);
        o.z = f2bf(acc[mi][nj][2] + bv); o.w = f2bf(acc[mi][nj][3] + bv);
        *(ushort4*)(Vt + ((size_t)(bb_ * 16 + h) * HS + d) * TSEQ + tt) = o;
      }
    }
  }
}

// Proj GEMM epilogue -> fp32 out + bias
__global__ __launch_bounds__(256) void gemm_proj_bf16(
    const u16* __restrict__ Ab, const u16* __restrict__ Btr,
    const float* __restrict__ bias, float* __restrict__ C) {
  GEMM_MAIN_LOOP(Ab, Btr, N_EMBD)
#pragma unroll
  for (int nj = 0; nj < 4; ++nj) {
    int n = bn + wc * 64 + nj * 16 + lrow;
    float bv = bias[n];
#pragma unroll
    for (int mi = 0; mi < 4; ++mi) {
      int mbase = bm + wr * 64 + mi * 16 + lhi * 4;
#pragma unroll
      for (int r = 0; r < 4; ++r)
        C[(size_t)(mbase + r) * N_EMBD + n] = acc[mi][nj][r] + bv;
    }
  }
}

// ---------------- MFMA flash attention v13 (R17-proven): 64 q-rows per wave
__device__ __forceinline__ void stage_kv(const u16* __restrict__ Kh,
                                         const u16* __restrict__ Vh,
                                         int kb, u16* kbuf, u16* vbuf,
                                         int tid, int w) {
#pragma unroll
  for (int i = 0; i < 2; ++i) {
    int s = i * 256 + tid;
    int r = s >> 3, c = s & 7;
    int cs = c ^ (r & 7);                      // pre-swizzled global source
    const u16* ksrc = Kh + (size_t)(kb + r) * HS + cs * 8;
    u16* kdst = kbuf + (size_t)(i * 256 + (w << 6)) * 8;   // wave-uniform base
    __builtin_amdgcn_global_load_lds(
        (const __attribute__((address_space(1))) void*)ksrc,
        (__attribute__((address_space(3))) void*)kdst, 16, 0, 0);
    const u16* vsrc = Vh + (size_t)r * TSEQ + kb + cs * 8;
    u16* vdst = vbuf + (size_t)(i * 256 + (w << 6)) * 8;
    __builtin_amdgcn_global_load_lds(
        (const __attribute__((address_space(1))) void*)vsrc,
        (__attribute__((address_space(3))) void*)vdst, 16, 0, 0);
  }
}

__global__ __launch_bounds__(256, 2) void attn_part(
    const u16* __restrict__ Qb, const u16* __restrict__ Kb,
    const u16* __restrict__ Vt, u16* __restrict__ Y,
    float* PfLow, float* PfHi, float* __restrict__ Lf) {
  __shared__ u16 Ks[2][64 * HS];      // 32KB dbuf
  __shared__ u16 Vs[2][64 * HS];
  __shared__ u16 Plds[4][64][72];     // 36.9KB

  const int tid  = threadIdx.x;
  const int lane = tid & 63;
  const int w    = tid >> 6;
  const int lrow = lane & 15;
  const int lhi  = lane >> 4;

  const int wg  = blockIdx.x;                 // 0..543
  const int xcd = wg & 7;
  const int lin = wg >> 3;                    // 0..67
  const int bhl = lin / 17;                   // 0..3
  const int id  = lin % 17;
  const int bh  = (xcd << 2) | bhl;
  const int b   = bh >> 4, h = bh & 15;

  // longest-first unit decode
  int j, part, cnt, sid;
  if (id == 0)       { j = 2; part = 0;       cnt = 1; sid = -1; }      // 12
  else if (id <= 2)  { j = 4; part = id - 1;  cnt = 2; sid = id - 1; }  // 10,10
  else if (id <= 5)  { j = 6; part = id - 3;  cnt = 3; sid = id - 1; }  // 9,9,10
  else if (id <= 7)  { j = 3; part = id - 6;  cnt = 2; sid = id - 1; }  // 8,8
  else if (id <= 11) { j = 7; part = id - 8;  cnt = 4; sid = id - 1; }  // 8x4
  else if (id <= 14) { j = 5; part = id - 12; cnt = 3; sid = id - 1; }  // 8x3
  else if (id == 15) { j = 1; part = 0;       cnt = 1; sid = -1; }      // 8
  else               { j = 0; part = 0;       cnt = 1; sid = -1; }      // 4
  const int split  = (cnt > 1);
  const int tsteps = 4 * j + 4;
  const int s0 = (part * tsteps) / cnt;
  const int s1 = ((part + 1) * tsteps) / cnt;
  const int nsteps = s1 - s0;

  const u16* Qh = Qb + (size_t)bh * TSEQ * HS;
  const u16* Kh = Kb + (size_t)bh * TSEQ * HS;
  const u16* Vh = Vt + (size_t)bh * HS * TSEQ;

  const int q0 = j * 256 + w * 64;            // wave's rows q0..q0+63

  bf16x8 aq[8];
#pragma unroll
  for (int sub = 0; sub < 4; ++sub) {
    aq[2 * sub]     = *(const bf16x8*)(Qh + (size_t)(q0 + sub * 16 + lrow) * HS + lhi * 8);
    aq[2 * sub + 1] = *(const bf16x8*)(Qh + (size_t)(q0 + sub * 16 + lrow) * HS + 32 + lhi * 8);
  }

  bf16x8 ones;
#pragma unroll
  for (int i = 0; i < 8; ++i) ones[i] = (short)0x3F80;   // bf16 1.0

  f32x4 o[4][4], ol[4];
#pragma unroll
  for (int sub = 0; sub < 4; ++sub) {
    ol[sub] = (f32x4){0.f, 0.f, 0.f, 0.f};
#pragma unroll
    for (int ds = 0; ds < 4; ++ds) o[sub][ds] = (f32x4){0.f, 0.f, 0.f, 0.f};
  }

  int kb = s0 * 64;
  stage_kv(Kh, Vh, kb, Ks[0], Vs[0], tid, w);

  for (int t = 0; t < nsteps; ++t) {
    const int cur = t & 1;
    __syncthreads();
    if (t + 1 < nsteps)
      stage_kv(Kh, Vh, kb + 64, Ks[cur ^ 1], Vs[cur ^ 1], tid, w);

    const u16* Kc = Ks[cur];
    const u16* Vc = Vs[cur];

    // ---- phase A: QK^T — K frags shared across 4 subtiles
    f32x4 sacc[4][4];
#pragma unroll
    for (int s = 0; s < 4; ++s) {
      int r = s * 16 + lrow;
      bf16x8 k0 = *(const bf16x8*)(Kc + r * HS + ((lhi    ) ^ (r & 7)) * 8);
      bf16x8 k1 = *(const bf16x8*)(Kc + r * HS + ((lhi + 4) ^ (r & 7)) * 8);
#pragma unroll
      for (int sub = 0; sub < 4; ++sub) {
        f32x4 z = (f32x4){0.f, 0.f, 0.f, 0.f};
        z = __builtin_amdgcn_mfma_f32_16x16x32_bf16(aq[2 * sub], k0, z, 0, 0, 0);
        z = __builtin_amdgcn_mfma_f32_16x16x32_bf16(aq[2 * sub + 1], k1, z, 0, 0, 0);
        sacc[sub][s] = z;
      }
    }

    // ---- mask + static-max exp2 + P write
#pragma unroll
    for (int sub = 0; sub < 4; ++sub) {
      const int qbase = q0 + sub * 16;
      if (kb + 63 > qbase) {
#pragma unroll
        for (int s = 0; s < 4; ++s) {
          int kg = kb + 16 * s + lrow;
#pragma unroll
          for (int r = 0; r < 4; ++r)
            if (kg > qbase + lhi * 4 + r) sacc[sub][s][r] = -3.0e38f;
        }
      }
#pragma unroll
      for (int s = 0; s < 4; ++s)
#pragma unroll
        for (int r = 0; r < 4; ++r)
          Plds[w][sub * 16 + lhi * 4 + r][s * 16 + lrow] =
              f2bf_fast(exp2f(sacc[sub][s][r] - 16.0f));
    }

    // ---- phase B: PV + ones-column l — V frags shared across 4 subtiles
#pragma unroll
    for (int ks = 0; ks < 2; ++ks) {
      bf16x8 pa[4];
#pragma unroll
      for (int sub = 0; sub < 4; ++sub)
        pa[sub] = *(const bf16x8*)&Plds[w][sub * 16 + lrow][ks * 32 + lhi * 8];
#pragma unroll
      for (int sub = 0; sub < 4; ++sub)
        ol[sub] = __builtin_amdgcn_mfma_f32_16x16x32_bf16(pa[sub], ones, ol[sub], 0, 0, 0);
#pragma unroll
      for (int ds = 0; ds < 4; ++ds) {
        int vr = ds * 16 + lrow;
        bf16x8 vf = *(const bf16x8*)(Vc + vr * 64 + ((ks * 4 + lhi) ^ (vr & 7)) * 8);
#pragma unroll
        for (int sub = 0; sub < 4; ++sub)
          o[sub][ds] = __builtin_amdgcn_mfma_f32_16x16x32_bf16(pa[sub], vf, o[sub][ds], 0, 0, 0);
      }
    }
    kb += 64;
  }

  if (!split) {
    // ---- direct epilogue
#pragma unroll
    for (int sub = 0; sub < 4; ++sub)
#pragma unroll
      for (int r = 0; r < 4; ++r) {
        float inv = 1.0f / ol[sub][r];
        int q = q0 + sub * 16 + lhi * 4 + r;
#pragma unroll
        for (int ds = 0; ds < 4; ++ds)
          Y[((size_t)(b * TSEQ + q)) * N_EMBD + h * HS + ds * 16 + lrow] =
              f2bf(o[sub][ds][r] * inv);
      }
  } else {
    // ---- partial epilogue: fp32 o + f32 l (static-max scale: add to combine)
    const int slot = bh * 14 + sid;
    float* orow = (slot < 224)
                      ? (PfLow + (size_t)slot * 16384)
                      : (PfHi + (size_t)(slot - 224) * 16384);
#pragma unroll
    for (int sub = 0; sub < 4; ++sub)
#pragma unroll
      for (int r = 0; r < 4; ++r) {
        int row = w * 64 + sub * 16 + lhi * 4 + r;
#pragma unroll
        for (int ds = 0; ds < 4; ++ds)
          orow[row * 64 + ds * 16 + lrow] = o[sub][ds][r];
        if (lrow == 0) Lf[slot * 256 + row] = ol[sub][r];
      }
  }
}

// combine v2: PARALLEL — 2560 blocks (160 units x 16 row-groups), coalesced.
__global__ __launch_bounds__(256) void attn_combine(
    const float* PfLow, const float* PfHi, const float* __restrict__ Lf,
    u16* __restrict__ Y) {
  const int blk  = blockIdx.x;                // 0..2559
  const int unit = blk >> 4;                  // 0..159
  const int rgrp = blk & 15;                  // 0..15 (16 rows each)
  const int bh = unit / 5, u = unit % 5;
  const int b  = bh >> 4, h = bh & 15;
  int j, base, cnt;
  if (u == 0)      { j = 3; base = 5;  cnt = 2; }
  else if (u == 1) { j = 4; base = 0;  cnt = 2; }
  else if (u == 2) { j = 5; base = 11; cnt = 3; }
  else if (u == 3) { j = 6; base = 2;  cnt = 3; }
  else             { j = 7; base = 7;  cnt = 4; }
  const int slot0 = bh * 14 + base;

  const int tid  = threadIdx.x;
  const int d    = tid & 63;
  const int rloc = tid >> 6;                  // 0..3

#pragma unroll
  for (int p = 0; p < 4; ++p) {
    int row = rgrp * 16 + p * 4 + rloc;
    float l = 0.f, o = 0.f;
    for (int k = 0; k < cnt; ++k) {
      int slot = slot0 + k;
      const float* orow = (slot < 224)
                              ? (PfLow + (size_t)slot * 16384)
                              : (PfHi + (size_t)(slot - 224) * 16384);
      l += Lf[slot * 256 + row];
      o += orow[row * 64 + d];
    }
    int q = j * 256 + row;
    Y[((size_t)(b * TSEQ + q)) * N_EMBD + h * HS + d] = f2bf(o / l);
  }
}

extern "C" void kernel_launch(void* const* d_in, const int* in_sizes, int n_in,
                              void* d_out, int out_size, void* d_ws, size_t ws_size,
                              hipStream_t stream) {
  const float* x      = (const float*)d_in[0];
  const float* W_attn = (const float*)d_in[1];
  const float* b_attn = (const float*)d_in[2];
  const float* W_proj = (const float*)d_in[3];
  const float* b_proj = (const float*)d_in[4];
  float* out = (float*)d_out;

  u16* xb  = (u16*)d_ws;                              // dead after QKV GEMM
  u16* Wat = xb  + (size_t)BT * N_EMBD;               // dead after QKV GEMM
  u16* Wpt = Wat + (size_t)3 * N_EMBD * N_EMBD;       // kept (proj)
  u16* Qb  = Wpt + (size_t)N_EMBD * N_EMBD;
  u16* Kb  = Qb  + (size_t)BT * N_EMBD;
  u16* Vt  = Kb  + (size_t)BT * N_EMBD;
  u16* yb  = Vt  + (size_t)BT * N_EMBD;
  float* PfLow = (float*)d_ws;                        // 224 slots overlay xb+Wat (exact)
  float* PfHi  = (float*)(yb + (size_t)BT * N_EMBD);  // 224 slots * 64KB = 14.68MB
  float* Lf    = PfHi + (size_t)224 * 16384;          // 448*256 f32 = 0.46MB

  prep_all<<<8192, 256, 0, stream>>>(x, W_attn, W_proj, xb, Wat, Wpt);
  {
    dim3 grid(3 * N_EMBD / 128, BT / 128);
    gemm_qkv_bf16<<<grid, 256, 0, stream>>>(xb, Wat, b_attn, Qb, Kb, Vt);
  }
  {
    attn_part<<<544, 256, 0, stream>>>(Qb, Kb, Vt, yb, PfLow, PfHi, Lf);
    attn_combine<<<2560, 256, 0, stream>>>(PfLow, PfHi, Lf, yb);
  }
  {
    dim3 grid(N_EMBD / 128, BT / 128);
    gemm_proj_bf16<<<grid, 256, 0, stream>>>(yb, Wpt, b_proj, out);
  }
}

// Round 19
// 128.970 us; speedup vs baseline: 1.5690x; 1.0648x over previous
//
#include <hip/hip_runtime.h>
#include <hip/hip_bf16.h>
#include <math.h>

#define N_EMBD 1024
#define N_HEAD 16
#define HS 64
#define BT 4096
#define TSEQ 2048

typedef float f32x4 __attribute__((ext_vector_type(4)));
typedef short bf16x8 __attribute__((ext_vector_type(8)));
typedef unsigned short u16;

static __device__ __forceinline__ u16 f2bf(float f) {
  union { float f; unsigned int u; } c; c.f = f;
  unsigned int r = c.u + 0x7FFFu + ((c.u >> 16) & 1u);   // RNE
  return (u16)(r >> 16);
}

static __device__ __forceinline__ u16 f2bf_fast(float f) {
  union { __hip_bfloat16 h; u16 u; } cv;
  cv.h = __float2bfloat16(f);
  return cv.u;
}

// ---------------- fused prep: x->bf16 ; W_attn,W_proj -> bf16 transposed
__global__ __launch_bounds__(256) void prep_all(
    const float* __restrict__ x, const float* __restrict__ Wa,
    const float* __restrict__ Wp, u16* __restrict__ xb,
    u16* __restrict__ Wat, u16* __restrict__ Wpt) {
  const int bid = blockIdx.x;
  const int t = threadIdx.x;
  if (bid < 4096) {
    int i = bid * 256 + t;
    float4 v = ((const float4*)x)[i];
    ushort4 o;
    o.x = f2bf(v.x); o.y = f2bf(v.y); o.z = f2bf(v.z); o.w = f2bf(v.w);
    ((ushort4*)xb)[i] = o;
    return;
  }
  __shared__ u16 Ls[32][36];
  const float* W; u16* Wt; int K, N, n0, k0;
  if (bid < 7168) {
    int g = bid - 4096;                       // 96 x 32
    W = Wa; Wt = Wat; K = N_EMBD; N = 3 * N_EMBD;
    n0 = (g % 96) * 32; k0 = (g / 96) * 32;
  } else {
    int g = bid - 7168;                       // 32 x 32
    W = Wp; Wt = Wpt; K = N_EMBD; N = N_EMBD;
    n0 = (g % 32) * 32; k0 = (g / 32) * 32;
  }
  {
    int kk = t >> 3, nn4 = (t & 7) * 4;
    float4 v = *(const float4*)(W + (size_t)(k0 + kk) * N + n0 + nn4);
    Ls[kk][nn4 + 0] = f2bf(v.x); Ls[kk][nn4 + 1] = f2bf(v.y);
    Ls[kk][nn4 + 2] = f2bf(v.z); Ls[kk][nn4 + 3] = f2bf(v.w);
  }
  __syncthreads();
  {
    int nn = t >> 3, kk4 = (t & 7) * 4;
    ushort4 o;
    o.x = Ls[kk4 + 0][nn]; o.y = Ls[kk4 + 1][nn];
    o.z = Ls[kk4 + 2][nn]; o.w = Ls[kk4 + 3][nn];
    *(ushort4*)(Wt + (size_t)(n0 + nn) * K + k0 + kk4) = o;
  }
}

// ---------------- bf16 MFMA GEMM core (m97 structure + T1 XCD swizzle)
#define BKS 32

__device__ __forceinline__ int swz(int row, int c) {
  return row * 4 + (c ^ ((row >> 1) & 3));
}

__device__ __forceinline__ void stage128x32(const u16* __restrict__ G, int ldk,
                                            u16* lds, int w, int lane) {
#pragma unroll
  for (int i = 0; i < 2; ++i) {
    int s = i * 256 + w * 64 + lane;
    int row = s >> 2, c = s & 3;
    int csrc = c ^ ((row >> 1) & 3);
    const u16* src = G + (size_t)row * ldk + csrc * 8;
    u16* dst = lds + (size_t)(i * 256 + w * 64) * 8;
    __builtin_amdgcn_global_load_lds(
        (const __attribute__((address_space(1))) void*)src,
        (__attribute__((address_space(3))) void*)dst, 16, 0, 0);
  }
}

#define GEMM_MAIN_LOOP(Aptr, Bptr, Kdim)                                        \
  __shared__ u16 sm[2][2][128 * BKS];                                           \
  const int tid = threadIdx.x, lane = tid & 63, w = tid >> 6;                   \
  const int wr = w >> 1, wc = w & 1, lrow = lane & 15, lhi = lane >> 4;         \
  const int _lin = blockIdx.y * gridDim.x + blockIdx.x;                         \
  const int _cpx = (gridDim.x * gridDim.y) >> 3;                                \
  const int _swz = (_lin & 7) * _cpx + (_lin >> 3);                             \
  const int bm = (_swz / gridDim.x) * 128, bn = (_swz % gridDim.x) * 128;       \
  f32x4 acc[4][4];                                                              \
  _Pragma("unroll") for (int i = 0; i < 4; ++i)                                 \
      _Pragma("unroll") for (int j = 0; j < 4; ++j)                             \
          acc[i][j] = (f32x4){0.f, 0.f, 0.f, 0.f};                              \
  stage128x32(Aptr + (size_t)bm * Kdim, Kdim, sm[0][0], w, lane);               \
  stage128x32(Bptr + (size_t)bn * Kdim, Kdim, sm[0][1], w, lane);               \
  __syncthreads();                                                              \
  const int NT = Kdim / BKS;                                                    \
  for (int t = 0; t < NT; ++t) {                                                \
    int cur = t & 1, nxt = cur ^ 1;                                             \
    if (t + 1 < NT) {                                                           \
      stage128x32(Aptr + (size_t)bm * Kdim + (t + 1) * BKS, Kdim, sm[nxt][0],   \
                  w, lane);                                                     \
      stage128x32(Bptr + (size_t)bn * Kdim + (t + 1) * BKS, Kdim, sm[nxt][1],   \
                  w, lane);                                                     \
    }                                                                           \
    const u16* As = sm[cur][0];                                                 \
    const u16* Bs = sm[cur][1];                                                 \
    bf16x8 af[4], bfr[4];                                                       \
    _Pragma("unroll") for (int mi = 0; mi < 4; ++mi) {                          \
      int row = wr * 64 + mi * 16 + lrow;                                       \
      af[mi] = *(const bf16x8*)(As + (size_t)swz(row, lhi) * 8);                \
    }                                                                           \
    _Pragma("unroll") for (int nj = 0; nj < 4; ++nj) {                          \
      int row = wc * 64 + nj * 16 + lrow;                                       \
      bfr[nj] = *(const bf16x8*)(Bs + (size_t)swz(row, lhi) * 8);               \
    }                                                                           \
    _Pragma("unroll") for (int mi = 0; mi < 4; ++mi)                            \
        _Pragma("unroll") for (int nj = 0; nj < 4; ++nj)                        \
            acc[mi][nj] = __builtin_amdgcn_mfma_f32_16x16x32_bf16(              \
                af[mi], bfr[nj], acc[mi][nj], 0, 0, 0);                         \
    __syncthreads();                                                            \
  }

// QKV GEMM epilogue -> Qb (scaled by 0.125*log2e), Kb, Vt
__global__ __launch_bounds__(256) void gemm_qkv_bf16(
    const u16* __restrict__ Ab, const u16* __restrict__ Btr,
    const float* __restrict__ bias,
    u16* __restrict__ Qb, u16* __restrict__ Kb, u16* __restrict__ Vt) {
  GEMM_MAIN_LOOP(Ab, Btr, N_EMBD)
  const int sector = bn >> 10;
  const float QSC = 0.125f * 1.44269504f;
#pragma unroll
  for (int nj = 0; nj < 4; ++nj) {
    int n = bn + wc * 64 + nj * 16 + lrow;
    int h = (n & 1023) >> 6, d = n & 63;
    float bv = bias[n];
#pragma unroll
    for (int mi = 0; mi < 4; ++mi) {
      int mbase = bm + wr * 64 + mi * 16 + lhi * 4;
      int bb_ = mbase >> 11, tt = mbase & 2047;
      if (sector == 0) {
#pragma unroll
        for (int r = 0; r < 4; ++r)
          Qb[((size_t)(bb_ * 16 + h) * TSEQ + tt + r) * HS + d] =
              f2bf((acc[mi][nj][r] + bv) * QSC);
      } else if (sector == 1) {
#pragma unroll
        for (int r = 0; r < 4; ++r)
          Kb[((size_t)(bb_ * 16 + h) * TSEQ + tt + r) * HS + d] =
              f2bf(acc[mi][nj][r] + bv);
      } else {
        ushort4 o;
        o.x = f2bf(acc[mi][nj][0] + bv); o.y = f2bf(acc[mi][nj][1] + bv);
        o.z = f2bf(acc[mi][nj][2] + bv); o.w = f2bf(acc[mi][nj][3] + bv);
        *(ushort4*)(Vt + ((size_t)(bb_ * 16 + h) * HS + d) * TSEQ + tt) = o;
      }
    }
  }
}

// Proj GEMM epilogue -> fp32 out + bias
__global__ __launch_bounds__(256) void gemm_proj_bf16(
    const u16* __restrict__ Ab, const u16* __restrict__ Btr,
    const float* __restrict__ bias, float* __restrict__ C) {
  GEMM_MAIN_LOOP(Ab, Btr, N_EMBD)
#pragma unroll
  for (int nj = 0; nj < 4; ++nj) {
    int n = bn + wc * 64 + nj * 16 + lrow;
    float bv = bias[n];
#pragma unroll
    for (int mi = 0; mi < 4; ++mi) {
      int mbase = bm + wr * 64 + mi * 16 + lhi * 4;
#pragma unroll
      for (int r = 0; r < 4; ++r)
        C[(size_t)(mbase + r) * N_EMBD + n] = acc[mi][nj][r] + bv;
    }
  }
}

// ---------------- MFMA flash attention (R14-proven geometry + T5 setprio)
// 4 waves/block, wave = 32 q-rows; block covers 128 rows of one bh.
// j<8: one block, full k-range, direct y write. j>=8: TWO blocks (k halves),
// fp32 partials combined by plain addition (static-max softmax). 768 blocks.
__device__ __forceinline__ void stage_kv(const u16* __restrict__ Kh,
                                         const u16* __restrict__ Vh,
                                         int kb, u16* kbuf, u16* vbuf,
                                         int tid, int w) {
#pragma unroll
  for (int i = 0; i < 2; ++i) {
    int s = i * 256 + tid;
    int r = s >> 3, c = s & 7;
    int cs = c ^ (r & 7);                      // pre-swizzled global source
    const u16* ksrc = Kh + (size_t)(kb + r) * HS + cs * 8;
    u16* kdst = kbuf + (size_t)(i * 256 + (w << 6)) * 8;   // wave-uniform base
    __builtin_amdgcn_global_load_lds(
        (const __attribute__((address_space(1))) void*)ksrc,
        (__attribute__((address_space(3))) void*)kdst, 16, 0, 0);
    const u16* vsrc = Vh + (size_t)r * TSEQ + kb + cs * 8;
    u16* vdst = vbuf + (size_t)(i * 256 + (w << 6)) * 8;
    __builtin_amdgcn_global_load_lds(
        (const __attribute__((address_space(1))) void*)vsrc,
        (__attribute__((address_space(3))) void*)vdst, 16, 0, 0);
  }
}

__global__ __launch_bounds__(256, 2) void attn_part(
    const u16* __restrict__ Qb, const u16* __restrict__ Kb,
    const u16* __restrict__ Vt, u16* __restrict__ Y,
    float* __restrict__ Pf, float* __restrict__ Lf) {
  __shared__ u16 Ks[2][64 * HS];
  __shared__ u16 Vs[2][64 * HS];
  __shared__ u16 Plds[4][32][72];

  const int tid  = threadIdx.x;
  const int lane = tid & 63;
  const int w    = tid >> 6;
  const int lrow = lane & 15;
  const int lhi  = lane >> 4;

  const int wg  = blockIdx.x;                 // 0..767
  const int xcd = wg & 7;
  const int lin = wg >> 3;                    // 0..95
  const int bhl = lin / 24;                   // 0..3
  const int p   = lin % 24;                   // part index within bh
  int j, half, split;
  if (p < 16) { j = 15 - (p >> 1); half = p & 1; split = 1; }
  else        { j = 23 - p;        half = 0;     split = 0; }
  const int bh = (xcd << 2) | bhl;
  const int b  = bh >> 4, h = bh & 15;

  const u16* Qh = Qb + (size_t)bh * TSEQ * HS;
  const u16* Kh = Kb + (size_t)bh * TSEQ * HS;
  const u16* Vh = Vt + (size_t)bh * HS * TSEQ;

  const int q0 = j * 128 + w * 32;            // wave's rows q0..q0+31
  const int nsteps = split ? (j + 1) : (2 * j + 2);
  int kb = split ? (half * (j + 1) * 64) : 0;

  bf16x8 aq[4];
  aq[0] = *(const bf16x8*)(Qh + (size_t)(q0 + lrow) * HS + lhi * 8);
  aq[1] = *(const bf16x8*)(Qh + (size_t)(q0 + lrow) * HS + 32 + lhi * 8);
  aq[2] = *(const bf16x8*)(Qh + (size_t)(q0 + 16 + lrow) * HS + lhi * 8);
  aq[3] = *(const bf16x8*)(Qh + (size_t)(q0 + 16 + lrow) * HS + 32 + lhi * 8);

  bf16x8 ones;
#pragma unroll
  for (int i = 0; i < 8; ++i) ones[i] = (short)0x3F80;   // bf16 1.0

  f32x4 o[2][4], ol[2];
#pragma unroll
  for (int sub = 0; sub < 2; ++sub) {
    ol[sub] = (f32x4){0.f, 0.f, 0.f, 0.f};
#pragma unroll
    for (int ds = 0; ds < 4; ++ds) o[sub][ds] = (f32x4){0.f, 0.f, 0.f, 0.f};
  }

  stage_kv(Kh, Vh, kb, Ks[0], Vs[0], tid, w);

  for (int t = 0; t < nsteps; ++t) {
    const int cur = t & 1;
    __syncthreads();
    if (t + 1 < nsteps)
      stage_kv(Kh, Vh, kb + 64, Ks[cur ^ 1], Vs[cur ^ 1], tid, w);

    const u16* Kc = Ks[cur];
    const u16* Vc = Vs[cur];

    // ---- phase A: QK^T (both subtiles share K frags) — T5 setprio
    f32x4 sacc[2][4];
    __builtin_amdgcn_s_setprio(1);
#pragma unroll
    for (int s = 0; s < 4; ++s) {
      int r = s * 16 + lrow;
      bf16x8 k0 = *(const bf16x8*)(Kc + r * HS + ((lhi    ) ^ (r & 7)) * 8);
      bf16x8 k1 = *(const bf16x8*)(Kc + r * HS + ((lhi + 4) ^ (r & 7)) * 8);
      f32x4 z0 = (f32x4){0.f, 0.f, 0.f, 0.f};
      f32x4 z1 = (f32x4){0.f, 0.f, 0.f, 0.f};
      z0 = __builtin_amdgcn_mfma_f32_16x16x32_bf16(aq[0], k0, z0, 0, 0, 0);
      z0 = __builtin_amdgcn_mfma_f32_16x16x32_bf16(aq[1], k1, z0, 0, 0, 0);
      z1 = __builtin_amdgcn_mfma_f32_16x16x32_bf16(aq[2], k0, z1, 0, 0, 0);
      z1 = __builtin_amdgcn_mfma_f32_16x16x32_bf16(aq[3], k1, z1, 0, 0, 0);
      sacc[0][s] = z0; sacc[1][s] = z1;
    }
    __builtin_amdgcn_s_setprio(0);

    // ---- mask + static-max exp2 + P write
#pragma unroll
    for (int sub = 0; sub < 2; ++sub) {
      const int qbase = q0 + sub * 16;
      if (kb + 63 > qbase) {
#pragma unroll
        for (int s = 0; s < 4; ++s) {
          int kg = kb + 16 * s + lrow;
#pragma unroll
          for (int r = 0; r < 4; ++r)
            if (kg > qbase + lhi * 4 + r) sacc[sub][s][r] = -3.0e38f;
        }
      }
#pragma unroll
      for (int s = 0; s < 4; ++s)
#pragma unroll
        for (int r = 0; r < 4; ++r)
          Plds[w][sub * 16 + lhi * 4 + r][s * 16 + lrow] =
              f2bf_fast(exp2f(sacc[sub][s][r] - 16.0f));
    }

    // ---- phase B: PV + ones-column l — T5 setprio
    __builtin_amdgcn_s_setprio(1);
#pragma unroll
    for (int ks = 0; ks < 2; ++ks) {
      bf16x8 pa0 = *(const bf16x8*)&Plds[w][lrow][ks * 32 + lhi * 8];
      bf16x8 pa1 = *(const bf16x8*)&Plds[w][16 + lrow][ks * 32 + lhi * 8];
      ol[0] = __builtin_amdgcn_mfma_f32_16x16x32_bf16(pa0, ones, ol[0], 0, 0, 0);
      ol[1] = __builtin_amdgcn_mfma_f32_16x16x32_bf16(pa1, ones, ol[1], 0, 0, 0);
#pragma unroll
      for (int ds = 0; ds < 4; ++ds) {
        int vr = ds * 16 + lrow;
        bf16x8 vf = *(const bf16x8*)(Vc + vr * 64 + ((ks * 4 + lhi) ^ (vr & 7)) * 8);
        o[0][ds] = __builtin_amdgcn_mfma_f32_16x16x32_bf16(pa0, vf, o[0][ds], 0, 0, 0);
        o[1][ds] = __builtin_amdgcn_mfma_f32_16x16x32_bf16(pa1, vf, o[1][ds], 0, 0, 0);
      }
    }
    __builtin_amdgcn_s_setprio(0);
    kb += 64;
  }

  if (!split) {
#pragma unroll
    for (int sub = 0; sub < 2; ++sub)
#pragma unroll
      for (int r = 0; r < 4; ++r) {
        float inv = 1.0f / ol[sub][r];
        int q = q0 + sub * 16 + lhi * 4 + r;
#pragma unroll
        for (int ds = 0; ds < 4; ++ds)
          Y[((size_t)(b * TSEQ + q)) * N_EMBD + h * HS + ds * 16 + lrow] =
              f2bf(o[sub][ds][r] * inv);
      }
  } else {
    // ---- partial epilogue: fp32 o and l (same 2^-16 scale -> add to combine)
    const int slot = (((bh << 3) | (j - 8)) << 1) | half;
    float* orow = Pf + (size_t)slot * (128 * 64);
#pragma unroll
    for (int sub = 0; sub < 2; ++sub)
#pragma unroll
      for (int r = 0; r < 4; ++r) {
        int row = w * 32 + sub * 16 + lhi * 4 + r;
#pragma unroll
        for (int ds = 0; ds < 4; ++ds)
          orow[row * 64 + ds * 16 + lrow] = o[sub][ds][r];
        if (lrow == 0) Lf[slot * 128 + row] = ol[sub][r];
      }
  }
}

// combine: one block per split q-block (bh, j>=8); add the two halves.
__global__ __launch_bounds__(256) void attn_combine(
    const float* __restrict__ Pf, const float* __restrict__ Lf,
    u16* __restrict__ Y) {
  const int bi = blockIdx.x;                  // 0..255
  const int bh = bi >> 3, jj = 8 + (bi & 7);
  const int b  = bh >> 4, h = bh & 15;
  const int s0 = (((bh << 3) | (jj - 8)) << 1);
  const int tid = threadIdx.x;
  const int d   = tid & 63;
  const int rg  = tid >> 6;                   // 0..3

  const float* o0 = Pf + (size_t)s0 * (128 * 64);
  const float* o1 = o0 + (128 * 64);
  for (int rr = 0; rr < 32; ++rr) {
    int row = rg * 32 + rr;
    float l = Lf[s0 * 128 + row] + Lf[(s0 + 1) * 128 + row];
    float o = o0[row * 64 + d] + o1[row * 64 + d];
    int q = jj * 128 + row;
    Y[((size_t)(b * TSEQ + q)) * N_EMBD + h * HS + d] = f2bf(o / l);
  }
}

extern "C" void kernel_launch(void* const* d_in, const int* in_sizes, int n_in,
                              void* d_out, int out_size, void* d_ws, size_t ws_size,
                              hipStream_t stream) {
  const float* x      = (const float*)d_in[0];
  const float* W_attn = (const float*)d_in[1];
  const float* b_attn = (const float*)d_in[2];
  const float* W_proj = (const float*)d_in[3];
  const float* b_proj = (const float*)d_in[4];
  float* out = (float*)d_out;

  u16* xb  = (u16*)d_ws;
  u16* Wat = xb  + (size_t)BT * N_EMBD;
  u16* Wpt = Wat + (size_t)3 * N_EMBD * N_EMBD;
  u16* Qb  = Wpt + (size_t)N_EMBD * N_EMBD;
  u16* Kb  = Qb  + (size_t)BT * N_EMBD;
  u16* Vt  = Kb  + (size_t)BT * N_EMBD;
  u16* yb  = Vt  + (size_t)BT * N_EMBD;
  float* Pf = (float*)(yb + (size_t)BT * N_EMBD);     // 512 slots * 8192 f32 = 16MB
  float* Lf = Pf + (size_t)512 * 128 * 64;            // 512*128 f32

  prep_all<<<8192, 256, 0, stream>>>(x, W_attn, W_proj, xb, Wat, Wpt);
  {
    dim3 grid(3 * N_EMBD / 128, BT / 128);
    gemm_qkv_bf16<<<grid, 256, 0, stream>>>(xb, Wat, b_attn, Qb, Kb, Vt);
  }
  {
    attn_part<<<768, 256, 0, stream>>>(Qb, Kb, Vt, yb, Pf, Lf);
    attn_combine<<<256, 256, 0, stream>>>(Pf, Lf, yb);
  }
  {
    dim3 grid(N_EMBD / 128, BT / 128);
    gemm_proj_bf16<<<grid, 256, 0, stream>>>(yb, Wpt, b_proj, out);
  }
}